// Round 2
// baseline (13685.661 us; speedup 1.0000x reference)
//
#include <hip/hip_runtime.h>
#include <math.h>

#define DEV __device__ __forceinline__

// ---------------- problem dims ----------------
static constexpr int BB   = 128;     // batch
static constexpr int NN   = 300;     // tgt & memory seq len
static constexpr int DM   = 512;     // d_model

// ---------------- helpers ----------------
DEV unsigned short f2bf(float f) {
  unsigned u = __float_as_uint(f);
  unsigned r = (u + 0x7fffu + ((u >> 16) & 1u)) >> 16;
  return (unsigned short)r;
}
DEV unsigned pack_bf16x2(float a, float b) {
  return (unsigned)f2bf(a) | ((unsigned)f2bf(b) << 16);
}
DEV float blo(unsigned u) { return __uint_as_float(u << 16); }
DEV float bhi(unsigned u) { return __uint_as_float(u & 0xffff0000u); }

// =================== LayerNorm (one wave per row of 512) ===================
__global__ __launch_bounds__(256) void ln_kernel(
    const float* __restrict__ X, const float* __restrict__ g,
    const float* __restrict__ b, float* __restrict__ Y, int rows)
{
  int wv = threadIdx.x >> 6, lane = threadIdx.x & 63;
  int row = blockIdx.x * 4 + wv;
  if (row >= rows) return;
  const float* xp = X + (size_t)row * DM;
  float v[8]; float s = 0.f, s2 = 0.f;
#pragma unroll
  for (int j = 0; j < 8; j++) {
    v[j] = xp[lane + 64 * j]; s += v[j]; s2 += v[j] * v[j];
  }
#pragma unroll
  for (int o = 32; o >= 1; o >>= 1) { s += __shfl_xor(s, o); s2 += __shfl_xor(s2, o); }
  float mean = s * (1.f / 512.f);
  float var  = s2 * (1.f / 512.f) - mean * mean;
  float rstd = rsqrtf(var + 1e-5f);
  float* yp = Y + (size_t)row * DM;
#pragma unroll
  for (int j = 0; j < 8; j++) {
    int c = lane + 64 * j;
    yp[c] = (v[j] - mean) * rstd * g[c] + b[c];
  }
}

// =================== generic fp32 GEMM ===================
// C[m,c] = sum_k A[m,k] * (TRANSB ? W[c,k] : W[k,c])  (+ epilogue)
// EPI: 0 plain, 1 +bias, 2 relu(+bias), 3 +bias+R, 4 accumulate into C (no bias)
// 128x128 tile, BK=16, 256 threads, 8x8 microtile. Handles arbitrary M via
// clamp-on-load / guard-on-store (K must be a multiple of 16).
template<int TRANSB, int EPI>
__global__ __launch_bounds__(256) void gemm_f32(
    const float* __restrict__ A, int lda,
    const float* __restrict__ W, int ldw,
    const float* __restrict__ bias,
    const float* __restrict__ R, int ldr,
    float* __restrict__ C, int ldc,
    int M, int K, int NC)
{
  __shared__ float As[16][132];
  __shared__ float Bs[16][132];
  const int tid = threadIdx.x;
  const int n0 = blockIdx.x * 128;
  const int m0 = blockIdx.y * 128;
  const int tx = tid & 15, ty = tid >> 4;
  const int arow = tid >> 1, akk = (tid & 1) * 8;
  const int bkr = tid >> 4, bnc = (tid & 15) * 8;
  int arowg = m0 + arow; if (arowg >= M) arowg = M - 1;  // clamp (values unused)

  float acc[8][8];
#pragma unroll
  for (int i = 0; i < 8; i++)
#pragma unroll
    for (int j = 0; j < 8; j++) acc[i][j] = 0.f;

  for (int k0 = 0; k0 < K; k0 += 16) {
    float4 a0 = *(const float4*)&A[(size_t)arowg * lda + k0 + akk];
    float4 a1 = *(const float4*)&A[(size_t)arowg * lda + k0 + akk + 4];
    float4 w0, w1;
    if (TRANSB) {
      int c = n0 + arow;
      if (c < NC) {
        w0 = *(const float4*)&W[(size_t)c * ldw + k0 + akk];
        w1 = *(const float4*)&W[(size_t)c * ldw + k0 + akk + 4];
      } else {
        w0 = make_float4(0.f, 0.f, 0.f, 0.f); w1 = w0;
      }
    } else {
      const float* wp = &W[(size_t)(k0 + bkr) * ldw + n0 + bnc];
      if (n0 + bnc + 7 < NC) {
        w0 = *(const float4*)wp; w1 = *(const float4*)(wp + 4);
      } else {
        float t0[8];
#pragma unroll
        for (int j = 0; j < 8; j++) t0[j] = (n0 + bnc + j < NC) ? wp[j] : 0.f;
        w0 = make_float4(t0[0], t0[1], t0[2], t0[3]);
        w1 = make_float4(t0[4], t0[5], t0[6], t0[7]);
      }
    }
    __syncthreads();
    As[akk + 0][arow] = a0.x; As[akk + 1][arow] = a0.y;
    As[akk + 2][arow] = a0.z; As[akk + 3][arow] = a0.w;
    As[akk + 4][arow] = a1.x; As[akk + 5][arow] = a1.y;
    As[akk + 6][arow] = a1.z; As[akk + 7][arow] = a1.w;
    if (TRANSB) {
      Bs[akk + 0][arow] = w0.x; Bs[akk + 1][arow] = w0.y;
      Bs[akk + 2][arow] = w0.z; Bs[akk + 3][arow] = w0.w;
      Bs[akk + 4][arow] = w1.x; Bs[akk + 5][arow] = w1.y;
      Bs[akk + 6][arow] = w1.z; Bs[akk + 7][arow] = w1.w;
    } else {
      *(float4*)&Bs[bkr][bnc]     = w0;
      *(float4*)&Bs[bkr][bnc + 4] = w1;
    }
    __syncthreads();
#pragma unroll
    for (int kk = 0; kk < 16; kk++) {
      float4 xa0 = *(const float4*)&As[kk][ty * 8];
      float4 xa1 = *(const float4*)&As[kk][ty * 8 + 4];
      float4 xb0 = *(const float4*)&Bs[kk][tx * 8];
      float4 xb1 = *(const float4*)&Bs[kk][tx * 8 + 4];
      float av[8] = {xa0.x, xa0.y, xa0.z, xa0.w, xa1.x, xa1.y, xa1.z, xa1.w};
      float bv[8] = {xb0.x, xb0.y, xb0.z, xb0.w, xb1.x, xb1.y, xb1.z, xb1.w};
#pragma unroll
      for (int i = 0; i < 8; i++)
#pragma unroll
        for (int j = 0; j < 8; j++) acc[i][j] += av[i] * bv[j];
    }
  }

#pragma unroll
  for (int i = 0; i < 8; i++) {
    int r = m0 + ty * 8 + i;
    if (r < M) {
      size_t rowc = (size_t)r * ldc;
#pragma unroll
      for (int j4 = 0; j4 < 8; j4 += 4) {
        int c = n0 + tx * 8 + j4;
        if (c + 3 < NC) {
          float e0 = acc[i][j4 + 0], e1 = acc[i][j4 + 1];
          float e2 = acc[i][j4 + 2], e3 = acc[i][j4 + 3];
          if (EPI == 1 || EPI == 2 || EPI == 3) {
            e0 += bias[c + 0]; e1 += bias[c + 1]; e2 += bias[c + 2]; e3 += bias[c + 3];
          }
          if (EPI == 2) {
            e0 = fmaxf(e0, 0.f); e1 = fmaxf(e1, 0.f);
            e2 = fmaxf(e2, 0.f); e3 = fmaxf(e3, 0.f);
          }
          if (EPI == 3) {
            size_t rr = (size_t)r * ldr + c;
            e0 += R[rr + 0]; e1 += R[rr + 1]; e2 += R[rr + 2]; e3 += R[rr + 3];
          }
          if (EPI == 4) {
            float4 old = *(const float4*)&C[rowc + c];
            e0 += old.x; e1 += old.y; e2 += old.z; e3 += old.w;
          }
          *(float4*)&C[rowc + c] = make_float4(e0, e1, e2, e3);
        } else {
#pragma unroll
          for (int jj = 0; jj < 4; jj++) {
            int cc = c + jj;
            if (cc < NC) {
              float e = acc[i][j4 + jj];
              if (EPI == 1 || EPI == 2 || EPI == 3) e += bias[cc];
              if (EPI == 2) e = fmaxf(e, 0.f);
              if (EPI == 3) e += R[(size_t)r * ldr + cc];
              if (EPI == 4) e += C[rowc + cc];
              C[rowc + cc] = e;
            }
          }
        }
      }
    }
  }
}

// =================== ds (kinematic-tree) attention ===================
// COMB: [rows,1248] (q | k), V: [rows,624] modified in place on channels
// h*156 + 3 .. h*156+146.  One half-wave (24 active lanes) per (row,head).
__global__ __launch_bounds__(256) void ds_attn_kernel(
    const float* __restrict__ COMB, float* __restrict__ V)
{
  __shared__ float ks[4][2][24][6];
  __shared__ float vs[4][2][24][6];
  int wv = threadIdx.x >> 6, lane = threadIdx.x & 63;
  int half = lane >> 5, i = lane & 31;
  int u  = blockIdx.x * 4 + wv;     // head-pair unit
  int bn = u >> 1, hp = u & 1;
  int h  = hp * 2 + half;
  size_t cbase = (size_t)bn * 1248 + h * 156 + 3;
  size_t vbase = (size_t)bn * 624  + h * 156 + 3;

  float q[6];
  if (i < 24) {
#pragma unroll
    for (int j = 0; j < 6; j++) {
      q[j]                 = COMB[cbase + i * 6 + j];
      ks[wv][half][i][j]   = COMB[cbase + 624 + i * 6 + j];
      vs[wv][half][i][j]   = V[vbase + i * 6 + j];
    }
  } else {
#pragma unroll
    for (int j = 0; j < 6; j++) q[j] = 0.f;
  }
  __syncthreads();

  float p[24];
#pragma unroll
  for (int k = 0; k < 24; k++) p[k] = 0.f;

  if (i < 24) {
    float mx = -1e30f;
#pragma unroll
    for (int k = 0; k < 24; k++) {
      float s = 0.f;
#pragma unroll
      for (int j = 0; j < 6; j++) s += q[j] * ks[wv][half][k][j];
      s *= 0.4082482904638631f;   // 1/sqrt(6)
      p[k] = s; mx = fmaxf(mx, s);
    }
    float sum = 0.f;
#pragma unroll
    for (int k = 0; k < 24; k++) { p[k] = __expf(p[k] - mx); sum += p[k]; }
    float inv = 1.f / sum;
#pragma unroll
    for (int k = 0; k < 24; k++) p[k] *= inv;
  }

  // _custom_weight: column-0 chain via width-32 shuffles (c = p[i][0]),
  // row-0 chain in-lane on lane 0.  The two chains touch disjoint elements.
  {
    float c = p[0];
    float t;
    t = __shfl(c, 3, 32);  if (i == 6) c = (c + t) * 0.5f;
    t = __shfl(c, 6, 32);  if (i == 9) c = (c + t) * 0.5f;
    t = __shfl(c, 9, 32);  if (i >= 12 && i <= 14) c = (c + t) * 0.5f;
    int src = (i >= 3) ? (i - 3) : 0;
    t = __shfl(c, src, 32); if (i >= 15 && i <= 17) c = (c + t) * 0.5f;
    p[0] = c;
  }
  if (i == 0) {
    p[6]  = (p[6]  + p[3])  * 0.5f;
    p[9]  = (p[9]  + p[6])  * 0.5f;
    p[12] = (p[12] + p[9])  * 0.5f;
    p[13] = (p[13] + p[9])  * 0.5f;
    p[14] = (p[14] + p[9])  * 0.5f;
    p[16] = (p[16] + p[13]) * 0.5f;
    p[17] = (p[17] + p[14]) * 0.5f;
    p[15] = (p[15] + p[12]) * 0.5f;
  }

  if (i < 24) {
    float o[6] = {0.f, 0.f, 0.f, 0.f, 0.f, 0.f};
#pragma unroll
    for (int k = 0; k < 24; k++) {
#pragma unroll
      for (int j = 0; j < 6; j++) o[j] += p[k] * vs[wv][half][k][j];
    }
#pragma unroll
    for (int j = 0; j < 6; j++) V[vbase + i * 6 + j] = o[j];
  }
}

// =================== fused MHA (self & cross), dh=64, 8 heads ===================
// Block per (b,h), b chunk-local. K staged bf16 [300][68] (136B rows ->
// conflict-free b64 reads), V staged transposed bf16 [64][300].
// One wave per query; softmax via 64-lane shuffle reductions; p via shfl.
__global__ __launch_bounds__(256) void mha_kernel(
    const float* __restrict__ Qp, int ldq, int qoff,
    const float* __restrict__ KVp, int ldkv, int koff, int voff,
    float* __restrict__ Op, float scale)
{
  __shared__ unsigned short Ksh[300][68];
  __shared__ unsigned short Vt[64][300];
  const int bh = blockIdx.x, b = bh >> 3, h = bh & 7;
  const int tid = threadIdx.x, wv = tid >> 6, lane = tid & 63;
  const size_t kvbase = (size_t)b * NN * ldkv;

  for (int f = tid; f < NN * 32; f += 256) {
    int kk = f >> 5, dp = (f & 31) * 2;
    const float* src = KVp + kvbase + (size_t)kk * ldkv + koff + h * 64 + dp;
    float2 xv = *(const float2*)src;
    *(unsigned*)&Ksh[kk][dp] = pack_bf16x2(xv.x, xv.y);
  }
  for (int f = tid; f < 150 * 64; f += 256) {
    int kp = f >> 6, d = f & 63;
    const float* src = KVp + kvbase + (size_t)(2 * kp) * ldkv + voff + h * 64 + d;
    float v0 = src[0], v1 = src[ldkv];
    *(unsigned*)&Vt[d][2 * kp] = pack_bf16x2(v0, v1);
  }
  __syncthreads();

  for (int n = wv; n < NN; n += 4) {
    float qv = Qp[(size_t)(b * NN + n) * ldq + qoff + h * 64 + lane];
    float acc0 = 0.f, acc1 = 0.f, acc2 = 0.f, acc3 = 0.f, acc4 = 0.f;
#pragma unroll
    for (int d4 = 0; d4 < 16; d4++) {
      float q0 = __shfl(qv, d4 * 4 + 0);
      float q1 = __shfl(qv, d4 * 4 + 1);
      float q2 = __shfl(qv, d4 * 4 + 2);
      float q3 = __shfl(qv, d4 * 4 + 3);
      uint2 kr;
      kr = *(const uint2*)&Ksh[lane][d4 * 4];
      acc0 += q0 * blo(kr.x) + q1 * bhi(kr.x) + q2 * blo(kr.y) + q3 * bhi(kr.y);
      kr = *(const uint2*)&Ksh[lane + 64][d4 * 4];
      acc1 += q0 * blo(kr.x) + q1 * bhi(kr.x) + q2 * blo(kr.y) + q3 * bhi(kr.y);
      kr = *(const uint2*)&Ksh[lane + 128][d4 * 4];
      acc2 += q0 * blo(kr.x) + q1 * bhi(kr.x) + q2 * blo(kr.y) + q3 * bhi(kr.y);
      kr = *(const uint2*)&Ksh[lane + 192][d4 * 4];
      acc3 += q0 * blo(kr.x) + q1 * bhi(kr.x) + q2 * blo(kr.y) + q3 * bhi(kr.y);
      if (lane < 44) {
        kr = *(const uint2*)&Ksh[lane + 256][d4 * 4];
        acc4 += q0 * blo(kr.x) + q1 * bhi(kr.x) + q2 * blo(kr.y) + q3 * bhi(kr.y);
      }
    }
    float p0 = acc0 * scale, p1 = acc1 * scale, p2 = acc2 * scale, p3 = acc3 * scale;
    float p4 = (lane < 44) ? acc4 * scale : -1e30f;
    float mx = fmaxf(fmaxf(fmaxf(p0, p1), fmaxf(p2, p3)), p4);
#pragma unroll
    for (int o = 32; o >= 1; o >>= 1) mx = fmaxf(mx, __shfl_xor(mx, o));
    p0 = __expf(p0 - mx); p1 = __expf(p1 - mx);
    p2 = __expf(p2 - mx); p3 = __expf(p3 - mx);
    p4 = (lane < 44) ? __expf(p4 - mx) : 0.f;
    float s = p0 + p1 + p2 + p3 + p4;
#pragma unroll
    for (int o = 32; o >= 1; o >>= 1) s += __shfl_xor(s, o);
    float inv = 1.f / s;
    p0 *= inv; p1 *= inv; p2 *= inv; p3 *= inv; p4 *= inv;

    float outv = 0.f;
#define AV_BLOCK(PT, T5, GMAX)                                                   \
    _Pragma("unroll")                                                            \
    for (int g = 0; g < GMAX; g++) {                                             \
      uint2 vv = *(const uint2*)&Vt[lane][(T5) * 64 + g * 4];                    \
      float w0 = __shfl(PT, g * 4 + 0), w1 = __shfl(PT, g * 4 + 1);              \
      float w2 = __shfl(PT, g * 4 + 2), w3 = __shfl(PT, g * 4 + 3);              \
      outv += w0 * blo(vv.x) + w1 * bhi(vv.x) + w2 * blo(vv.y) + w3 * bhi(vv.y); \
    }
    AV_BLOCK(p0, 0, 16)
    AV_BLOCK(p1, 1, 16)
    AV_BLOCK(p2, 2, 16)
    AV_BLOCK(p3, 3, 16)
    AV_BLOCK(p4, 4, 11)
#undef AV_BLOCK
    Op[(size_t)(b * NN + n) * DM + h * 64 + lane] = outv;
  }
}

// =================== column mean over seq + mish(t + mean) ===================
// grid covers Bc*512 threads exactly; b is chunk-local.
__global__ __launch_bounds__(256) void colmean_mish(
    const float* __restrict__ Y, const float* __restrict__ tvec,
    float* __restrict__ mm)
{
  int g = blockIdx.x * 256 + threadIdx.x;
  int b = g >> 9, d = g & 511;
  const float* yp = Y + (size_t)b * NN * DM + d;
  float s = 0.f;
  for (int n = 0; n < NN; n++) s += yp[(size_t)n * DM];
  float v = tvec[g] + s * (1.f / 300.f);
  float sp = (v > 20.f) ? v : log1pf(__expf(v));
  mm[g] = v * tanhf(sp);
}

// =================== X += (Hw+1)*Y + Hb ===================
__global__ __launch_bounds__(256) void align_apply(
    float* __restrict__ X, const float* __restrict__ Y,
    const float* __restrict__ H)
{
  int idx = blockIdx.x * 256 + threadIdx.x;  // over rows*128 float4s
  int row = idx >> 7;
  int d4  = (idx & 127) * 4;
  int b   = row / NN;
  float4 y = *(const float4*)&Y[(size_t)row * DM + d4];
  float4 x = *(const float4*)&X[(size_t)row * DM + d4];
  const float* hw = H + (size_t)b * 1024 + d4;
  const float* hb = hw + 512;
  x.x += (hw[0] + 1.f) * y.x + hb[0];
  x.y += (hw[1] + 1.f) * y.y + hb[1];
  x.z += (hw[2] + 1.f) * y.z + hb[2];
  x.w += (hw[3] + 1.f) * y.w + hb[3];
  *(float4*)&X[(size_t)row * DM + d4] = x;
}

// =================== launch ===================
extern "C" void kernel_launch(void* const* d_in, const int* in_sizes, int n_in,
                              void* d_out, int out_size, void* d_ws, size_t ws_size,
                              hipStream_t stream)
{
  const float* tgt      = (const float*)d_in[0];
  const float* memory   = (const float*)d_in[1];
  const float* tvec     = (const float*)d_in[2];
  const float* qk_w     = (const float*)d_in[3];
  const float* v_w      = (const float*)d_in[4];
  const float* ds_lw    = (const float*)d_in[5];
  const float* ds_lb    = (const float*)d_in[6];
  const float* ta_in_w  = (const float*)d_in[7];
  const float* ta_in_b  = (const float*)d_in[8];
  const float* ta_out_w = (const float*)d_in[9];
  const float* ta_out_b = (const float*)d_in[10];
  const float* ca_in_w  = (const float*)d_in[11];
  const float* ca_in_b  = (const float*)d_in[12];
  const float* ca_out_w = (const float*)d_in[13];
  const float* ca_out_b = (const float*)d_in[14];
  const float* l1_w     = (const float*)d_in[15];
  const float* l1_b     = (const float*)d_in[16];
  const float* l2_w     = (const float*)d_in[17];
  const float* l2_b     = (const float*)d_in[18];
  const float* n1_g = (const float*)d_in[19]; const float* n1_b = (const float*)d_in[20];
  const float* n2_g = (const float*)d_in[21]; const float* n2_b = (const float*)d_in[22];
  const float* n3_g = (const float*)d_in[23]; const float* n3_b = (const float*)d_in[24];
  const float* n4_g = (const float*)d_in[25]; const float* n4_b = (const float*)d_in[26];
  const float* a1_w = (const float*)d_in[27]; const float* a1_b = (const float*)d_in[28];
  const float* a2_w = (const float*)d_in[29]; const float* a2_b = (const float*)d_in[30];
  const float* a3_w = (const float*)d_in[31]; const float* a3_b = (const float*)d_in[32];

  // Batch-chunked: every op in the forward is independent per batch element.
  // Per-batch-element workspace: (300*(512+1536+1024+512) + 512 + 1024) floats
  //   = 1,076,736 floats = 4,306,944 bytes.
  const size_t per_b = 4306944ULL;
  int Bc = 128;
  while (Bc > 1 && (size_t)Bc * per_b > ws_size) Bc >>= 1;
  const int rows = Bc * NN;            // rows per chunk
  const int mB   = (rows + 127) / 128; // gemm m-blocks per chunk
  const int nchunks = BB / Bc;

  float* ws0 = (float*)d_ws;
  float* XN = ws0;                     // [rows,512]
  float* T1 = XN + (size_t)rows * 512; // [rows,1536]
  float* T2 = T1 + (size_t)rows * 1536;// [rows,1024]
  float* Yb = T2 + (size_t)rows * 1024;// [rows,512]
  float* MM = Yb + (size_t)rows * 512; // [Bc,512]
  float* Hb = MM + (size_t)Bc * 512;   // [Bc,1024]

  dim3 thr(256);

  for (int c = 0; c < nchunks; ++c) {
    const size_t roff = (size_t)c * Bc * NN * DM;
    const float* tgtC = tgt    + roff;
    const float* memC = memory + roff;
    const float* tC   = tvec   + (size_t)c * Bc * 512;
    float*       XC   = (float*)d_out + roff;

    // ---- ds-attention branch: x = tgt + ds_attn(LN1(tgt)) ----
    ln_kernel<<<rows / 4, thr, 0, stream>>>(tgtC, n1_g, n1_b, XN, rows);
    gemm_f32<0,0><<<dim3(10,mB), thr, 0, stream>>>(XN,512, qk_w,1248, nullptr, nullptr,0, T1,1248, rows,512,1248);
    gemm_f32<0,0><<<dim3(5,mB),  thr, 0, stream>>>(XN,512, v_w,624,   nullptr, nullptr,0, T2,624,  rows,512,624);
    ds_attn_kernel<<<rows / 2, thr, 0, stream>>>(T1, T2);
    gemm_f32<1,3><<<dim3(4,mB),  thr, 0, stream>>>(T2,624, ds_lw,624, ds_lb, tgtC,512, XC,512, rows,624,512);

    // ---- self attention + align1 ----
    ln_kernel<<<rows / 4, thr, 0, stream>>>(XC, n2_g, n2_b, XN, rows);
    gemm_f32<1,1><<<dim3(12,mB), thr, 0, stream>>>(XN,512, ta_in_w,512, ta_in_b, nullptr,0, T1,1536, rows,512,1536);
    mha_kernel<<<Bc * 8, thr, 0, stream>>>(T1,1536,0, T1,1536,512,1024, XN, 0.125f);
    gemm_f32<1,1><<<dim3(4,mB),  thr, 0, stream>>>(XN,512, ta_out_w,512, ta_out_b, nullptr,0, Yb,512, rows,512,512);
    colmean_mish<<<Bc * 2, thr, 0, stream>>>(Yb, tC, MM);
    gemm_f32<1,1><<<dim3(8,1),   thr, 0, stream>>>(MM,512, a1_w,512, a1_b, nullptr,0, Hb,1024, Bc,512,1024);
    align_apply<<<rows / 2, thr, 0, stream>>>(XC, Yb, Hb);

    // ---- cross attention + align2 ----
    ln_kernel<<<rows / 4, thr, 0, stream>>>(XC, n3_g, n3_b, XN, rows);
    gemm_f32<1,1><<<dim3(4,mB),  thr, 0, stream>>>(XN,512, ca_in_w,512, ca_in_b, nullptr,0, T1,512, rows,512,512);
    gemm_f32<1,1><<<dim3(8,mB),  thr, 0, stream>>>(memC,512, ca_in_w+262144,512, ca_in_b+512, nullptr,0, T2,1024, rows,512,1024);
    mha_kernel<<<Bc * 8, thr, 0, stream>>>(T1,512,0, T2,1024,0,512, XN, 0.125f);
    gemm_f32<1,1><<<dim3(4,mB),  thr, 0, stream>>>(XN,512, ca_out_w,512, ca_out_b, nullptr,0, Yb,512, rows,512,512);
    colmean_mish<<<Bc * 2, thr, 0, stream>>>(Yb, tC, MM);
    gemm_f32<1,1><<<dim3(8,1),   thr, 0, stream>>>(MM,512, a2_w,512, a2_b, nullptr,0, Hb,1024, Bc,512,1024);
    align_apply<<<rows / 2, thr, 0, stream>>>(XC, Yb, Hb);

    // ---- FFN (split D_FF into 2x1024 halves to bound workspace) + align3 ----
    ln_kernel<<<rows / 4, thr, 0, stream>>>(XC, n4_g, n4_b, XN, rows);
    gemm_f32<1,2><<<dim3(8,mB),  thr, 0, stream>>>(XN,512, l1_w,512, l1_b, nullptr,0, T2,1024, rows,512,1024);
    gemm_f32<1,1><<<dim3(4,mB),  thr, 0, stream>>>(T2,1024, l2_w,2048, l2_b, nullptr,0, Yb,512, rows,1024,512);
    gemm_f32<1,2><<<dim3(8,mB),  thr, 0, stream>>>(XN,512, l1_w+524288,512, l1_b+1024, nullptr,0, T2,1024, rows,512,1024);
    gemm_f32<1,4><<<dim3(4,mB),  thr, 0, stream>>>(T2,1024, l2_w+1024,2048, nullptr, nullptr,0, Yb,512, rows,1024,512);
    colmean_mish<<<Bc * 2, thr, 0, stream>>>(Yb, tC, MM);
    gemm_f32<1,1><<<dim3(8,1),   thr, 0, stream>>>(MM,512, a3_w,512, a3_b, nullptr,0, Hb,1024, Bc,512,1024);
    align_apply<<<rows / 2, thr, 0, stream>>>(XC, Yb, Hb);
  }
}

// Round 3
// 5525.735 us; speedup vs baseline: 2.4767x; 2.4767x over previous
//
#include <hip/hip_runtime.h>
#include <math.h>

#define DEV __device__ __forceinline__

// ---------------- problem dims ----------------
static constexpr int BB   = 128;     // batch
static constexpr int NN   = 300;     // tgt & memory seq len
static constexpr int DM   = 512;     // d_model

typedef __attribute__((ext_vector_type(8))) short short8;   // 8 bf16 = 4 VGPR
typedef __attribute__((ext_vector_type(4))) float f32x4;

// ---------------- helpers ----------------
DEV unsigned short f2bf(float f) {
  unsigned u = __float_as_uint(f);
  unsigned r = (u + 0x7fffu + ((u >> 16) & 1u)) >> 16;
  return (unsigned short)r;
}
DEV unsigned pack_bf16x2(float a, float b) {
  return (unsigned)f2bf(a) | ((unsigned)f2bf(b) << 16);
}
DEV float blo(unsigned u) { return __uint_as_float(u << 16); }
DEV float bhi(unsigned u) { return __uint_as_float(u & 0xffff0000u); }

// =================== LayerNorm (one wave per row of 512) ===================
__global__ __launch_bounds__(256) void ln_kernel(
    const float* __restrict__ X, const float* __restrict__ g,
    const float* __restrict__ b, float* __restrict__ Y, int rows)
{
  int wv = threadIdx.x >> 6, lane = threadIdx.x & 63;
  int row = blockIdx.x * 4 + wv;
  if (row >= rows) return;
  const float* xp = X + (size_t)row * DM;
  float v[8]; float s = 0.f, s2 = 0.f;
#pragma unroll
  for (int j = 0; j < 8; j++) {
    v[j] = xp[lane + 64 * j]; s += v[j]; s2 += v[j] * v[j];
  }
#pragma unroll
  for (int o = 32; o >= 1; o >>= 1) { s += __shfl_xor(s, o); s2 += __shfl_xor(s2, o); }
  float mean = s * (1.f / 512.f);
  float var  = s2 * (1.f / 512.f) - mean * mean;
  float rstd = rsqrtf(var + 1e-5f);
  float* yp = Y + (size_t)row * DM;
#pragma unroll
  for (int j = 0; j < 8; j++) {
    int c = lane + 64 * j;
    yp[c] = (v[j] - mean) * rstd * g[c] + b[c];
  }
}

// =================== fp32 transpose (for einsum weights) ===================
// out[c][r] = in[r][c];  in: [R][Ccols]
__global__ __launch_bounds__(256) void transpose_f32(
    const float* __restrict__ in, float* __restrict__ out, int R, int Ccols)
{
  __shared__ float t[32][33];
  int c0 = blockIdx.x * 32, r0 = blockIdx.y * 32;
  int x = threadIdx.x & 31, y = threadIdx.x >> 5;   // y in 0..7
#pragma unroll
  for (int dy = 0; dy < 32; dy += 8) {
    int r = r0 + y + dy, c = c0 + x;
    t[y + dy][x] = (r < R && c < Ccols) ? in[(size_t)r * Ccols + c] : 0.f;
  }
  __syncthreads();
#pragma unroll
  for (int dy = 0; dy < 32; dy += 8) {
    int c = c0 + y + dy, r = r0 + x;
    if (c < Ccols && r < R) out[(size_t)c * R + r] = t[x][y + dy];
  }
}

// =================== bf16 MFMA GEMM ===================
// C[m,n] = sum_k A[m,k] * W[n,k]   (both operands k-major; fp32 in, bf16 MFMA)
// EPI: 0 plain, 1 +bias, 2 relu(+bias), 3 +bias+R, 4 accumulate into C
// 128x128 tile, BK=32, 256 thr = 4 waves (2x2), 16x mfma_16x16x32_bf16/wave/step.
// Arbitrary M, NC (clamp-on-load / guard-on-store); K must be a multiple of 16.
template<int EPI>
__global__ __launch_bounds__(256) void gemm_bf16(
    const float* __restrict__ A, int lda,
    const float* __restrict__ W, int ldw,
    const float* __restrict__ bias,
    const float* __restrict__ R, int ldr,
    float* __restrict__ C, int ldc,
    int M, int K, int NC)
{
  // row stride 40 bf16 (80 B): 8-row bank period covers all 32 banks -> 2-way max (free)
  __shared__ unsigned short As[128 * 40];
  __shared__ unsigned short Bs[128 * 40];
  const int tid = threadIdx.x;
  const int wave = tid >> 6, lane = tid & 63;
  const int wr = wave >> 1, wc = wave & 1;
  const int quad = lane >> 4, l16 = lane & 15;
  const int n0 = blockIdx.x * 128;
  const int m0 = blockIdx.y * 128;
  const int srow = tid >> 1;          // 0..127
  const int skk  = (tid & 1) * 16;    // 0 or 16

  f32x4 acc[4][4];
#pragma unroll
  for (int i = 0; i < 4; i++)
#pragma unroll
    for (int j = 0; j < 4; j++) acc[i][j] = (f32x4){0.f, 0.f, 0.f, 0.f};

  int ar = m0 + srow; if (ar >= M)  ar = M - 1;   // clamp; dup rows unused on store
  int br = n0 + srow; if (br >= NC) br = NC - 1;
  const float* apr = A + (size_t)ar * lda;
  const float* bpr = W + (size_t)br * ldw;

  for (int k0 = 0; k0 < K; k0 += 32) {
    float4 a0, a1, a2, a3, b0, b1, b2, b3;
    if (k0 + skk < K) {            // K % 16 == 0 -> whole 16-seg in or out
      const float* ap = apr + k0 + skk;
      const float* bp = bpr + k0 + skk;
      a0 = *(const float4*)(ap);      a1 = *(const float4*)(ap + 4);
      a2 = *(const float4*)(ap + 8);  a3 = *(const float4*)(ap + 12);
      b0 = *(const float4*)(bp);      b1 = *(const float4*)(bp + 4);
      b2 = *(const float4*)(bp + 8);  b3 = *(const float4*)(bp + 12);
    } else {
      a0 = a1 = a2 = a3 = make_float4(0.f, 0.f, 0.f, 0.f);
      b0 = b1 = b2 = b3 = a0;
    }
    __syncthreads();   // prior iteration's frag reads done
    {
      uint4 p0 = make_uint4(pack_bf16x2(a0.x, a0.y), pack_bf16x2(a0.z, a0.w),
                            pack_bf16x2(a1.x, a1.y), pack_bf16x2(a1.z, a1.w));
      uint4 p1 = make_uint4(pack_bf16x2(a2.x, a2.y), pack_bf16x2(a2.z, a2.w),
                            pack_bf16x2(a3.x, a3.y), pack_bf16x2(a3.z, a3.w));
      *(uint4*)&As[srow * 40 + skk]     = p0;
      *(uint4*)&As[srow * 40 + skk + 8] = p1;
      uint4 q0 = make_uint4(pack_bf16x2(b0.x, b0.y), pack_bf16x2(b0.z, b0.w),
                            pack_bf16x2(b1.x, b1.y), pack_bf16x2(b1.z, b1.w));
      uint4 q1 = make_uint4(pack_bf16x2(b2.x, b2.y), pack_bf16x2(b2.z, b2.w),
                            pack_bf16x2(b3.x, b3.y), pack_bf16x2(b3.z, b3.w));
      *(uint4*)&Bs[srow * 40 + skk]     = q0;
      *(uint4*)&Bs[srow * 40 + skk + 8] = q1;
    }
    __syncthreads();
    short8 af[4], bf[4];
#pragma unroll
    for (int i = 0; i < 4; i++)
      af[i] = *(const short8*)&As[(wr * 64 + i * 16 + l16) * 40 + quad * 8];
#pragma unroll
    for (int j = 0; j < 4; j++)
      bf[j] = *(const short8*)&Bs[(wc * 64 + j * 16 + l16) * 40 + quad * 8];
#pragma unroll
    for (int i = 0; i < 4; i++)
#pragma unroll
      for (int j = 0; j < 4; j++)
        acc[i][j] = __builtin_amdgcn_mfma_f32_16x16x32_bf16(af[i], bf[j], acc[i][j], 0, 0, 0);
  }

  // epilogue: D[row=quad*4+r][col=lane&15] per 16x16 tile
#pragma unroll
  for (int i = 0; i < 4; i++) {
    int rbase = m0 + wr * 64 + i * 16 + quad * 4;
#pragma unroll
    for (int r = 0; r < 4; r++) {
      int row = rbase + r;
      if (row < M) {
        size_t rowc = (size_t)row * ldc;
#pragma unroll
        for (int j = 0; j < 4; j++) {
          int col = n0 + wc * 64 + j * 16 + l16;
          if (col < NC) {
            float e = acc[i][j][r];
            if (EPI == 1 || EPI == 2 || EPI == 3) e += bias[col];
            if (EPI == 2) e = fmaxf(e, 0.f);
            if (EPI == 3) e += R[(size_t)row * ldr + col];
            if (EPI == 4) e += C[rowc + col];
            C[rowc + col] = e;
          }
        }
      }
    }
  }
}

// =================== ds (kinematic-tree) attention ===================
__global__ __launch_bounds__(256) void ds_attn_kernel(
    const float* __restrict__ COMB, float* __restrict__ V)
{
  __shared__ float ks[4][2][24][6];
  __shared__ float vs[4][2][24][6];
  int wv = threadIdx.x >> 6, lane = threadIdx.x & 63;
  int half = lane >> 5, i = lane & 31;
  int u  = blockIdx.x * 4 + wv;     // head-pair unit
  int bn = u >> 1, hp = u & 1;
  int h  = hp * 2 + half;
  size_t cbase = (size_t)bn * 1248 + h * 156 + 3;
  size_t vbase = (size_t)bn * 624  + h * 156 + 3;

  float q[6];
  if (i < 24) {
#pragma unroll
    for (int j = 0; j < 6; j++) {
      q[j]                 = COMB[cbase + i * 6 + j];
      ks[wv][half][i][j]   = COMB[cbase + 624 + i * 6 + j];
      vs[wv][half][i][j]   = V[vbase + i * 6 + j];
    }
  } else {
#pragma unroll
    for (int j = 0; j < 6; j++) q[j] = 0.f;
  }
  __syncthreads();

  float p[24];
#pragma unroll
  for (int k = 0; k < 24; k++) p[k] = 0.f;

  if (i < 24) {
    float mx = -1e30f;
#pragma unroll
    for (int k = 0; k < 24; k++) {
      float s = 0.f;
#pragma unroll
      for (int j = 0; j < 6; j++) s += q[j] * ks[wv][half][k][j];
      s *= 0.4082482904638631f;   // 1/sqrt(6)
      p[k] = s; mx = fmaxf(mx, s);
    }
    float sum = 0.f;
#pragma unroll
    for (int k = 0; k < 24; k++) { p[k] = __expf(p[k] - mx); sum += p[k]; }
    float inv = 1.f / sum;
#pragma unroll
    for (int k = 0; k < 24; k++) p[k] *= inv;
  }

  {
    float c = p[0];
    float t;
    t = __shfl(c, 3, 32);  if (i == 6) c = (c + t) * 0.5f;
    t = __shfl(c, 6, 32);  if (i == 9) c = (c + t) * 0.5f;
    t = __shfl(c, 9, 32);  if (i >= 12 && i <= 14) c = (c + t) * 0.5f;
    int src = (i >= 3) ? (i - 3) : 0;
    t = __shfl(c, src, 32); if (i >= 15 && i <= 17) c = (c + t) * 0.5f;
    p[0] = c;
  }
  if (i == 0) {
    p[6]  = (p[6]  + p[3])  * 0.5f;
    p[9]  = (p[9]  + p[6])  * 0.5f;
    p[12] = (p[12] + p[9])  * 0.5f;
    p[13] = (p[13] + p[9])  * 0.5f;
    p[14] = (p[14] + p[9])  * 0.5f;
    p[16] = (p[16] + p[13]) * 0.5f;
    p[17] = (p[17] + p[14]) * 0.5f;
    p[15] = (p[15] + p[12]) * 0.5f;
  }

  if (i < 24) {
    float o[6] = {0.f, 0.f, 0.f, 0.f, 0.f, 0.f};
#pragma unroll
    for (int k = 0; k < 24; k++) {
#pragma unroll
      for (int j = 0; j < 6; j++) o[j] += p[k] * vs[wv][half][k][j];
    }
#pragma unroll
    for (int j = 0; j < 6; j++) V[vbase + i * 6 + j] = o[j];
  }
}

// =================== fused MHA (self & cross), dh=64, 8 heads ===================
// Block per (b,h), 512 threads (8 waves). __launch_bounds__(512,4) caps VGPR at
// 128 so 2 blocks (16 waves) fit per CU with the 79 KB LDS. One wave per query.
__global__ __launch_bounds__(512, 4) void mha_kernel(
    const float* __restrict__ Qp, int ldq, int qoff,
    const float* __restrict__ KVp, int ldkv, int koff, int voff,
    float* __restrict__ Op, float scale)
{
  __shared__ unsigned short Ksh[300][68];
  __shared__ unsigned short Vt[64][300];
  const int bh = blockIdx.x, b = bh >> 3, h = bh & 7;
  const int tid = threadIdx.x, wv = tid >> 6, lane = tid & 63;
  const size_t kvbase = (size_t)b * NN * ldkv;

  for (int f = tid; f < NN * 32; f += 512) {
    int kk = f >> 5, dp = (f & 31) * 2;
    const float* src = KVp + kvbase + (size_t)kk * ldkv + koff + h * 64 + dp;
    float2 xv = *(const float2*)src;
    *(unsigned*)&Ksh[kk][dp] = pack_bf16x2(xv.x, xv.y);
  }
  for (int f = tid; f < 150 * 64; f += 512) {
    int kp = f >> 6, d = f & 63;
    const float* src = KVp + kvbase + (size_t)(2 * kp) * ldkv + voff + h * 64 + d;
    float v0 = src[0], v1 = src[ldkv];
    *(unsigned*)&Vt[d][2 * kp] = pack_bf16x2(v0, v1);
  }
  __syncthreads();

  for (int n = wv; n < NN; n += 8) {
    float qv = Qp[(size_t)(b * NN + n) * ldq + qoff + h * 64 + lane];
    float acc0 = 0.f, acc1 = 0.f, acc2 = 0.f, acc3 = 0.f, acc4 = 0.f;
#pragma unroll 4
    for (int d4 = 0; d4 < 16; d4++) {
      float q0 = __shfl(qv, d4 * 4 + 0);
      float q1 = __shfl(qv, d4 * 4 + 1);
      float q2 = __shfl(qv, d4 * 4 + 2);
      float q3 = __shfl(qv, d4 * 4 + 3);
      uint2 kr;
      kr = *(const uint2*)&Ksh[lane][d4 * 4];
      acc0 += q0 * blo(kr.x) + q1 * bhi(kr.x) + q2 * blo(kr.y) + q3 * bhi(kr.y);
      kr = *(const uint2*)&Ksh[lane + 64][d4 * 4];
      acc1 += q0 * blo(kr.x) + q1 * bhi(kr.x) + q2 * blo(kr.y) + q3 * bhi(kr.y);
      kr = *(const uint2*)&Ksh[lane + 128][d4 * 4];
      acc2 += q0 * blo(kr.x) + q1 * bhi(kr.x) + q2 * blo(kr.y) + q3 * bhi(kr.y);
      kr = *(const uint2*)&Ksh[lane + 192][d4 * 4];
      acc3 += q0 * blo(kr.x) + q1 * bhi(kr.x) + q2 * blo(kr.y) + q3 * bhi(kr.y);
      if (lane < 44) {
        kr = *(const uint2*)&Ksh[lane + 256][d4 * 4];
        acc4 += q0 * blo(kr.x) + q1 * bhi(kr.x) + q2 * blo(kr.y) + q3 * bhi(kr.y);
      }
    }
    float p0 = acc0 * scale, p1 = acc1 * scale, p2 = acc2 * scale, p3 = acc3 * scale;
    float p4 = (lane < 44) ? acc4 * scale : -1e30f;
    float mx = fmaxf(fmaxf(fmaxf(p0, p1), fmaxf(p2, p3)), p4);
#pragma unroll
    for (int o = 32; o >= 1; o >>= 1) mx = fmaxf(mx, __shfl_xor(mx, o));
    p0 = __expf(p0 - mx); p1 = __expf(p1 - mx);
    p2 = __expf(p2 - mx); p3 = __expf(p3 - mx);
    p4 = (lane < 44) ? __expf(p4 - mx) : 0.f;
    float s = p0 + p1 + p2 + p3 + p4;
#pragma unroll
    for (int o = 32; o >= 1; o >>= 1) s += __shfl_xor(s, o);
    float inv = 1.f / s;
    p0 *= inv; p1 *= inv; p2 *= inv; p3 *= inv; p4 *= inv;

    // AV: 4 independent accumulation chains to break the serial FMA dependency
    float oa0 = 0.f, oa1 = 0.f, oa2 = 0.f, oa3 = 0.f;
#define AV_BLOCK(PT, T5, GMAX)                                                   \
    _Pragma("unroll 8")                                                          \
    for (int g = 0; g < GMAX; g++) {                                             \
      uint2 vv = *(const uint2*)&Vt[lane][(T5) * 64 + g * 4];                    \
      float w0 = __shfl(PT, g * 4 + 0), w1 = __shfl(PT, g * 4 + 1);              \
      float w2 = __shfl(PT, g * 4 + 2), w3 = __shfl(PT, g * 4 + 3);              \
      float pr = w0 * blo(vv.x) + w1 * bhi(vv.x) + w2 * blo(vv.y) + w3 * bhi(vv.y); \
      if ((g & 3) == 0) oa0 += pr; else if ((g & 3) == 1) oa1 += pr;             \
      else if ((g & 3) == 2) oa2 += pr; else oa3 += pr;                          \
    }
    AV_BLOCK(p0, 0, 16)
    AV_BLOCK(p1, 1, 16)
    AV_BLOCK(p2, 2, 16)
    AV_BLOCK(p3, 3, 16)
    AV_BLOCK(p4, 4, 11)
#undef AV_BLOCK
    Op[(size_t)(b * NN + n) * DM + h * 64 + lane] = (oa0 + oa1) + (oa2 + oa3);
  }
}

// =================== column mean over seq + mish(t + mean) ===================
__global__ __launch_bounds__(256) void colmean_mish(
    const float* __restrict__ Y, const float* __restrict__ tvec,
    float* __restrict__ mm)
{
  int g = blockIdx.x * 256 + threadIdx.x;
  int b = g >> 9, d = g & 511;
  const float* yp = Y + (size_t)b * NN * DM + d;
  float s = 0.f;
  for (int n = 0; n < NN; n++) s += yp[(size_t)n * DM];
  float v = tvec[g] + s * (1.f / 300.f);
  float sp = (v > 20.f) ? v : log1pf(__expf(v));
  mm[g] = v * tanhf(sp);
}

// =================== X += (Hw+1)*Y + Hb ===================
__global__ __launch_bounds__(256) void align_apply(
    float* __restrict__ X, const float* __restrict__ Y,
    const float* __restrict__ H)
{
  int idx = blockIdx.x * 256 + threadIdx.x;  // rows*128 float4s
  int row = idx >> 7;
  int d4  = (idx & 127) * 4;
  int b   = row / NN;
  float4 y = *(const float4*)&Y[(size_t)row * DM + d4];
  float4 x = *(const float4*)&X[(size_t)row * DM + d4];
  const float* hw = H + (size_t)b * 1024 + d4;
  const float* hb = hw + 512;
  x.x += (hw[0] + 1.f) * y.x + hb[0];
  x.y += (hw[1] + 1.f) * y.y + hb[1];
  x.z += (hw[2] + 1.f) * y.z + hb[2];
  x.w += (hw[3] + 1.f) * y.w + hb[3];
  *(float4*)&X[(size_t)row * DM + d4] = x;
}

// =================== launch ===================
extern "C" void kernel_launch(void* const* d_in, const int* in_sizes, int n_in,
                              void* d_out, int out_size, void* d_ws, size_t ws_size,
                              hipStream_t stream)
{
  const float* tgt      = (const float*)d_in[0];
  const float* memory   = (const float*)d_in[1];
  const float* tvec     = (const float*)d_in[2];
  const float* qk_w     = (const float*)d_in[3];
  const float* v_w      = (const float*)d_in[4];
  const float* ds_lw    = (const float*)d_in[5];
  const float* ds_lb    = (const float*)d_in[6];
  const float* ta_in_w  = (const float*)d_in[7];
  const float* ta_in_b  = (const float*)d_in[8];
  const float* ta_out_w = (const float*)d_in[9];
  const float* ta_out_b = (const float*)d_in[10];
  const float* ca_in_w  = (const float*)d_in[11];
  const float* ca_in_b  = (const float*)d_in[12];
  const float* ca_out_w = (const float*)d_in[13];
  const float* ca_out_b = (const float*)d_in[14];
  const float* l1_w     = (const float*)d_in[15];
  const float* l1_b     = (const float*)d_in[16];
  const float* l2_w     = (const float*)d_in[17];
  const float* l2_b     = (const float*)d_in[18];
  const float* n1_g = (const float*)d_in[19]; const float* n1_b = (const float*)d_in[20];
  const float* n2_g = (const float*)d_in[21]; const float* n2_b = (const float*)d_in[22];
  const float* n3_g = (const float*)d_in[23]; const float* n3_b = (const float*)d_in[24];
  const float* n4_g = (const float*)d_in[25]; const float* n4_b = (const float*)d_in[26];
  const float* a1_w = (const float*)d_in[27]; const float* a1_b = (const float*)d_in[28];
  const float* a2_w = (const float*)d_in[29]; const float* a2_b = (const float*)d_in[30];
  const float* a3_w = (const float*)d_in[31]; const float* a3_b = (const float*)d_in[32];

  // ws layout: transposed einsum weights first, then per-batch-chunk buffers.
  const size_t wtrans_f = 638976ULL + 319488ULL;   // qk_wT + v_wT (floats)
  const size_t per_b = 4306944ULL;                 // bytes per batch element
  int Bc = 128;
  while (Bc > 1 && wtrans_f * 4ULL + (size_t)Bc * per_b > ws_size) Bc >>= 1;
  const int rows = Bc * NN;
  const int mB   = (rows + 127) / 128;
  const int aB   = (Bc + 127) / 128;
  const int nchunks = BB / Bc;

  float* qkT = (float*)d_ws;               // [1248][512]
  float* vT  = qkT + 638976;               // [624][512]
  float* XN  = vT + 319488;                // [rows,512]
  float* T1  = XN + (size_t)rows * 512;    // [rows,1536]
  float* T2  = T1 + (size_t)rows * 1536;   // [rows,1024]
  float* Yb  = T2 + (size_t)rows * 1024;   // [rows,512]
  float* MM  = Yb + (size_t)rows * 512;    // [Bc,512]
  float* Hb  = MM + (size_t)Bc * 512;      // [Bc,1024]

  dim3 thr(256);

  // one-shot weight transposes (same work every call; graph-capture safe)
  transpose_f32<<<dim3(39, 16), thr, 0, stream>>>(qk_w, qkT, 512, 1248);
  transpose_f32<<<dim3(20, 16), thr, 0, stream>>>(v_w,  vT,  512, 624);

  for (int c = 0; c < nchunks; ++c) {
    const size_t roff = (size_t)c * Bc * NN * DM;
    const float* tgtC = tgt    + roff;
    const float* memC = memory + roff;
    const float* tC   = tvec   + (size_t)c * Bc * 512;
    float*       XC   = (float*)d_out + roff;

    // ---- ds-attention branch: x = tgt + ds_attn(LN1(tgt)) ----
    ln_kernel<<<rows / 4, thr, 0, stream>>>(tgtC, n1_g, n1_b, XN, rows);
    gemm_bf16<0><<<dim3(10, mB), thr, 0, stream>>>(XN, 512, qkT, 512, nullptr, nullptr, 0, T1, 1248, rows, 512, 1248);
    gemm_bf16<0><<<dim3(5, mB),  thr, 0, stream>>>(XN, 512, vT,  512, nullptr, nullptr, 0, T2, 624,  rows, 512, 624);
    ds_attn_kernel<<<rows / 2, thr, 0, stream>>>(T1, T2);
    gemm_bf16<3><<<dim3(4, mB),  thr, 0, stream>>>(T2, 624, ds_lw, 624, ds_lb, tgtC, 512, XC, 512, rows, 624, 512);

    // ---- self attention + align1 ----
    ln_kernel<<<rows / 4, thr, 0, stream>>>(XC, n2_g, n2_b, XN, rows);
    gemm_bf16<1><<<dim3(12, mB), thr, 0, stream>>>(XN, 512, ta_in_w, 512, ta_in_b, nullptr, 0, T1, 1536, rows, 512, 1536);
    mha_kernel<<<Bc * 8, 512, 0, stream>>>(T1, 1536, 0, T1, 1536, 512, 1024, XN, 0.125f);
    gemm_bf16<1><<<dim3(4, mB),  thr, 0, stream>>>(XN, 512, ta_out_w, 512, ta_out_b, nullptr, 0, Yb, 512, rows, 512, 512);
    colmean_mish<<<Bc * 2, thr, 0, stream>>>(Yb, tC, MM);
    gemm_bf16<1><<<dim3(8, aB),  thr, 0, stream>>>(MM, 512, a1_w, 512, a1_b, nullptr, 0, Hb, 1024, Bc, 512, 1024);
    align_apply<<<rows / 2, thr, 0, stream>>>(XC, Yb, Hb);

    // ---- cross attention + align2 ----
    ln_kernel<<<rows / 4, thr, 0, stream>>>(XC, n3_g, n3_b, XN, rows);
    gemm_bf16<1><<<dim3(4, mB),  thr, 0, stream>>>(XN, 512, ca_in_w, 512, ca_in_b, nullptr, 0, T1, 512, rows, 512, 512);
    gemm_bf16<1><<<dim3(8, mB),  thr, 0, stream>>>(memC, 512, ca_in_w + 262144, 512, ca_in_b + 512, nullptr, 0, T2, 1024, rows, 512, 1024);
    mha_kernel<<<Bc * 8, 512, 0, stream>>>(T1, 512, 0, T2, 1024, 0, 512, XN, 0.125f);
    gemm_bf16<1><<<dim3(4, mB),  thr, 0, stream>>>(XN, 512, ca_out_w, 512, ca_out_b, nullptr, 0, Yb, 512, rows, 512, 512);
    colmean_mish<<<Bc * 2, thr, 0, stream>>>(Yb, tC, MM);
    gemm_bf16<1><<<dim3(8, aB),  thr, 0, stream>>>(MM, 512, a2_w, 512, a2_b, nullptr, 0, Hb, 1024, Bc, 512, 1024);
    align_apply<<<rows / 2, thr, 0, stream>>>(XC, Yb, Hb);

    // ---- FFN (2x1024 halves) + align3 ----
    ln_kernel<<<rows / 4, thr, 0, stream>>>(XC, n4_g, n4_b, XN, rows);
    gemm_bf16<2><<<dim3(8, mB),  thr, 0, stream>>>(XN, 512, l1_w, 512, l1_b, nullptr, 0, T2, 1024, rows, 512, 1024);
    gemm_bf16<1><<<dim3(4, mB),  thr, 0, stream>>>(T2, 1024, l2_w, 2048, l2_b, nullptr, 0, Yb, 512, rows, 1024, 512);
    gemm_bf16<2><<<dim3(8, mB),  thr, 0, stream>>>(XN, 512, l1_w + 524288, 512, l1_b + 1024, nullptr, 0, T2, 1024, rows, 512, 1024);
    gemm_bf16<4><<<dim3(4, mB),  thr, 0, stream>>>(T2, 1024, l2_w + 1024, 2048, nullptr, nullptr, 0, Yb, 512, rows, 1024, 512);
    colmean_mish<<<Bc * 2, thr, 0, stream>>>(Yb, tC, MM);
    gemm_bf16<1><<<dim3(8, aB),  thr, 0, stream>>>(MM, 512, a3_w, 512, a3_b, nullptr, 0, Hb, 1024, Bc, 512, 1024);
    align_apply<<<rows / 2, thr, 0, stream>>>(XC, Yb, Hb);
  }
}

// Round 4
// 3057.275 us; speedup vs baseline: 4.4764x; 1.8074x over previous
//
#include <hip/hip_runtime.h>
#include <math.h>

#define DEV __device__ __forceinline__

// ---------------- problem dims ----------------
static constexpr int BB   = 128;     // batch
static constexpr int NN   = 300;     // tgt & memory seq len
static constexpr int DM   = 512;     // d_model

typedef __attribute__((ext_vector_type(8))) short short8;   // 8 bf16 = 4 VGPR
typedef __attribute__((ext_vector_type(4))) float f32x4;

// ---------------- helpers ----------------
DEV unsigned short f2bf(float f) {
  unsigned u = __float_as_uint(f);
  unsigned r = (u + 0x7fffu + ((u >> 16) & 1u)) >> 16;
  return (unsigned short)r;
}
DEV unsigned pack_bf16x2(float a, float b) {
  return (unsigned)f2bf(a) | ((unsigned)f2bf(b) << 16);
}
DEV unsigned pack_trunc(float a, float b) {   // truncate-to-bf16 pack (P in [0,1])
  return (__float_as_uint(a) >> 16) | (__float_as_uint(b) & 0xffff0000u);
}

// =================== LayerNorm (one wave per row of 512) ===================
__global__ __launch_bounds__(256) void ln_kernel(
    const float* __restrict__ X, const float* __restrict__ g,
    const float* __restrict__ b, float* __restrict__ Y, int rows)
{
  int wv = threadIdx.x >> 6, lane = threadIdx.x & 63;
  int row = blockIdx.x * 4 + wv;
  if (row >= rows) return;
  const float* xp = X + (size_t)row * DM;
  float v[8]; float s = 0.f, s2 = 0.f;
#pragma unroll
  for (int j = 0; j < 8; j++) {
    v[j] = xp[lane + 64 * j]; s += v[j]; s2 += v[j] * v[j];
  }
#pragma unroll
  for (int o = 32; o >= 1; o >>= 1) { s += __shfl_xor(s, o); s2 += __shfl_xor(s2, o); }
  float mean = s * (1.f / 512.f);
  float var  = s2 * (1.f / 512.f) - mean * mean;
  float rstd = rsqrtf(var + 1e-5f);
  float* yp = Y + (size_t)row * DM;
#pragma unroll
  for (int j = 0; j < 8; j++) {
    int c = lane + 64 * j;
    yp[c] = (v[j] - mean) * rstd * g[c] + b[c];
  }
}

// =================== fp32 transpose (for einsum weights) ===================
__global__ __launch_bounds__(256) void transpose_f32(
    const float* __restrict__ in, float* __restrict__ out, int R, int Ccols)
{
  __shared__ float t[32][33];
  int c0 = blockIdx.x * 32, r0 = blockIdx.y * 32;
  int x = threadIdx.x & 31, y = threadIdx.x >> 5;   // y in 0..7
#pragma unroll
  for (int dy = 0; dy < 32; dy += 8) {
    int r = r0 + y + dy, c = c0 + x;
    t[y + dy][x] = (r < R && c < Ccols) ? in[(size_t)r * Ccols + c] : 0.f;
  }
  __syncthreads();
#pragma unroll
  for (int dy = 0; dy < 32; dy += 8) {
    int c = c0 + y + dy, r = r0 + x;
    if (c < Ccols && r < R) out[(size_t)c * R + r] = t[x][y + dy];
  }
}

// =================== bf16 MFMA GEMM ===================
// C[m,n] = sum_k A[m,k] * W[n,k]   (both k-major; fp32 in, bf16 MFMA)
// EPI: 0 plain, 1 +bias, 2 relu(+bias), 3 +bias+R, 4 accumulate into C
template<int EPI>
__global__ __launch_bounds__(256) void gemm_bf16(
    const float* __restrict__ A, int lda,
    const float* __restrict__ W, int ldw,
    const float* __restrict__ bias,
    const float* __restrict__ R, int ldr,
    float* __restrict__ C, int ldc,
    int M, int K, int NC)
{
  __shared__ __align__(16) unsigned short As[128 * 40];
  __shared__ __align__(16) unsigned short Bs[128 * 40];
  const int tid = threadIdx.x;
  const int wave = tid >> 6, lane = tid & 63;
  const int wr = wave >> 1, wc = wave & 1;
  const int quad = lane >> 4, l16 = lane & 15;
  const int n0 = blockIdx.x * 128;
  const int m0 = blockIdx.y * 128;
  const int srow = tid >> 1;          // 0..127
  const int skk  = (tid & 1) * 16;    // 0 or 16

  f32x4 acc[4][4];
#pragma unroll
  for (int i = 0; i < 4; i++)
#pragma unroll
    for (int j = 0; j < 4; j++) acc[i][j] = (f32x4){0.f, 0.f, 0.f, 0.f};

  int ar = m0 + srow; if (ar >= M)  ar = M - 1;   // clamp; dup rows unused on store
  int br = n0 + srow; if (br >= NC) br = NC - 1;
  const float* apr = A + (size_t)ar * lda;
  const float* bpr = W + (size_t)br * ldw;

  for (int k0 = 0; k0 < K; k0 += 32) {
    float4 a0, a1, a2, a3, b0, b1, b2, b3;
    if (k0 + skk < K) {
      const float* ap = apr + k0 + skk;
      const float* bp = bpr + k0 + skk;
      a0 = *(const float4*)(ap);      a1 = *(const float4*)(ap + 4);
      a2 = *(const float4*)(ap + 8);  a3 = *(const float4*)(ap + 12);
      b0 = *(const float4*)(bp);      b1 = *(const float4*)(bp + 4);
      b2 = *(const float4*)(bp + 8);  b3 = *(const float4*)(bp + 12);
    } else {
      a0 = a1 = a2 = a3 = make_float4(0.f, 0.f, 0.f, 0.f);
      b0 = b1 = b2 = b3 = a0;
    }
    __syncthreads();
    {
      uint4 p0 = make_uint4(pack_bf16x2(a0.x, a0.y), pack_bf16x2(a0.z, a0.w),
                            pack_bf16x2(a1.x, a1.y), pack_bf16x2(a1.z, a1.w));
      uint4 p1 = make_uint4(pack_bf16x2(a2.x, a2.y), pack_bf16x2(a2.z, a2.w),
                            pack_bf16x2(a3.x, a3.y), pack_bf16x2(a3.z, a3.w));
      *(uint4*)&As[srow * 40 + skk]     = p0;
      *(uint4*)&As[srow * 40 + skk + 8] = p1;
      uint4 q0 = make_uint4(pack_bf16x2(b0.x, b0.y), pack_bf16x2(b0.z, b0.w),
                            pack_bf16x2(b1.x, b1.y), pack_bf16x2(b1.z, b1.w));
      uint4 q1 = make_uint4(pack_bf16x2(b2.x, b2.y), pack_bf16x2(b2.z, b2.w),
                            pack_bf16x2(b3.x, b3.y), pack_bf16x2(b3.z, b3.w));
      *(uint4*)&Bs[srow * 40 + skk]     = q0;
      *(uint4*)&Bs[srow * 40 + skk + 8] = q1;
    }
    __syncthreads();
    short8 af[4], bf[4];
#pragma unroll
    for (int i = 0; i < 4; i++)
      af[i] = *(const short8*)&As[(wr * 64 + i * 16 + l16) * 40 + quad * 8];
#pragma unroll
    for (int j = 0; j < 4; j++)
      bf[j] = *(const short8*)&Bs[(wc * 64 + j * 16 + l16) * 40 + quad * 8];
#pragma unroll
    for (int i = 0; i < 4; i++)
#pragma unroll
      for (int j = 0; j < 4; j++)
        acc[i][j] = __builtin_amdgcn_mfma_f32_16x16x32_bf16(af[i], bf[j], acc[i][j], 0, 0, 0);
  }

#pragma unroll
  for (int i = 0; i < 4; i++) {
    int rbase = m0 + wr * 64 + i * 16 + quad * 4;
#pragma unroll
    for (int r = 0; r < 4; r++) {
      int row = rbase + r;
      if (row < M) {
        size_t rowc = (size_t)row * ldc;
#pragma unroll
        for (int j = 0; j < 4; j++) {
          int col = n0 + wc * 64 + j * 16 + l16;
          if (col < NC) {
            float e = acc[i][j][r];
            if (EPI == 1 || EPI == 2 || EPI == 3) e += bias[col];
            if (EPI == 2) e = fmaxf(e, 0.f);
            if (EPI == 3) e += R[(size_t)row * ldr + col];
            if (EPI == 4) e += C[rowc + col];
            C[rowc + col] = e;
          }
        }
      }
    }
  }
}

// =================== ds (kinematic-tree) attention ===================
__global__ __launch_bounds__(256) void ds_attn_kernel(
    const float* __restrict__ COMB, float* __restrict__ V)
{
  __shared__ float ks[4][2][24][6];
  __shared__ float vs[4][2][24][6];
  int wv = threadIdx.x >> 6, lane = threadIdx.x & 63;
  int half = lane >> 5, i = lane & 31;
  int u  = blockIdx.x * 4 + wv;     // head-pair unit
  int bn = u >> 1, hp = u & 1;
  int h  = hp * 2 + half;
  size_t cbase = (size_t)bn * 1248 + h * 156 + 3;
  size_t vbase = (size_t)bn * 624  + h * 156 + 3;

  float q[6];
  if (i < 24) {
#pragma unroll
    for (int j = 0; j < 6; j++) {
      q[j]                 = COMB[cbase + i * 6 + j];
      ks[wv][half][i][j]   = COMB[cbase + 624 + i * 6 + j];
      vs[wv][half][i][j]   = V[vbase + i * 6 + j];
    }
  } else {
#pragma unroll
    for (int j = 0; j < 6; j++) q[j] = 0.f;
  }
  __syncthreads();

  float p[24];
#pragma unroll
  for (int k = 0; k < 24; k++) p[k] = 0.f;

  if (i < 24) {
    float mx = -1e30f;
#pragma unroll
    for (int k = 0; k < 24; k++) {
      float s = 0.f;
#pragma unroll
      for (int j = 0; j < 6; j++) s += q[j] * ks[wv][half][k][j];
      s *= 0.4082482904638631f;   // 1/sqrt(6)
      p[k] = s; mx = fmaxf(mx, s);
    }
    float sum = 0.f;
#pragma unroll
    for (int k = 0; k < 24; k++) { p[k] = __expf(p[k] - mx); sum += p[k]; }
    float inv = 1.f / sum;
#pragma unroll
    for (int k = 0; k < 24; k++) p[k] *= inv;
  }

  {
    float c = p[0];
    float t;
    t = __shfl(c, 3, 32);  if (i == 6) c = (c + t) * 0.5f;
    t = __shfl(c, 6, 32);  if (i == 9) c = (c + t) * 0.5f;
    t = __shfl(c, 9, 32);  if (i >= 12 && i <= 14) c = (c + t) * 0.5f;
    int src = (i >= 3) ? (i - 3) : 0;
    t = __shfl(c, src, 32); if (i >= 15 && i <= 17) c = (c + t) * 0.5f;
    p[0] = c;
  }
  if (i == 0) {
    p[6]  = (p[6]  + p[3])  * 0.5f;
    p[9]  = (p[9]  + p[6])  * 0.5f;
    p[12] = (p[12] + p[9])  * 0.5f;
    p[13] = (p[13] + p[9])  * 0.5f;
    p[14] = (p[14] + p[9])  * 0.5f;
    p[16] = (p[16] + p[13]) * 0.5f;
    p[17] = (p[17] + p[14]) * 0.5f;
    p[15] = (p[15] + p[12]) * 0.5f;
  }

  if (i < 24) {
    float o[6] = {0.f, 0.f, 0.f, 0.f, 0.f, 0.f};
#pragma unroll
    for (int k = 0; k < 24; k++) {
#pragma unroll
      for (int j = 0; j < 6; j++) o[j] += p[k] * vs[wv][half][k][j];
    }
#pragma unroll
    for (int j = 0; j < 6; j++) V[vbase + i * 6 + j] = o[j];
  }
}

// =================== MFMA MHA (self & cross), dh=64, 8 heads ===================
// Block per (b,h), 512 threads (8 waves). S' = K·Q^T so softmax over seq is
// in-lane; P transposed per 32-seq chunk via 1.25KB/wave LDS scratch; PV MFMA.
// K staged [304][72] bf16, V^T [64][328] bf16, both 16B-row-aligned, <=2-way
// bank aliasing (free). LDS total 96,000 B -> 1 block/CU, 8 waves.
__global__ __launch_bounds__(512) void mha_mfma(
    const float* __restrict__ Qp, int ldq, int qoff,
    const float* __restrict__ KVp, int ldkv, int koff, int voff,
    float* __restrict__ Op, float scale)
{
  __shared__ __align__(16) unsigned short Ksh[304 * 72];
  __shared__ __align__(16) unsigned short Vt[64 * 328];
  __shared__ __align__(16) unsigned short Pt[8][16 * 40];
  const int bh = blockIdx.x, b = bh >> 3, h = bh & 7;
  const int tid = threadIdx.x, wv = tid >> 6, lane = tid & 63;
  const int quad = lane >> 4, l16 = lane & 15;
  const size_t kbase = (size_t)b * NN * ldkv + koff + h * 64;
  const size_t vbase = (size_t)b * NN * ldkv + voff + h * 64;

  // ---- stage K: [300][64] f32 -> Ksh[304][72] bf16 (rows 300..303 zero) ----
  for (int f = tid; f < 304 * 16; f += 512) {
    int rk = f >> 4, c4 = (f & 15) * 4;
    uint2 w;
    if (rk < 300) {
      float4 kx = *(const float4*)(KVp + kbase + (size_t)rk * ldkv + c4);
      w.x = pack_bf16x2(kx.x, kx.y); w.y = pack_bf16x2(kx.z, kx.w);
    } else { w.x = 0u; w.y = 0u; }
    *(uint2*)&Ksh[rk * 72 + c4] = w;
  }
  // ---- stage V^T: Vt[d][seq], seq >= 300 zeroed ----
  for (int f = tid; f < 64 * 164; f += 512) {
    int d = f & 63, s0 = (f >> 6) * 2;
    unsigned w = 0u;
    if (s0 < 300) {
      float v0 = KVp[vbase + (size_t)s0 * ldkv + d];
      float v1 = (s0 + 1 < 300) ? KVp[vbase + (size_t)(s0 + 1) * ldkv + d] : 0.f;
      w = pack_bf16x2(v0, v1);
    }
    *(unsigned*)&Vt[d * 328 + s0] = w;
  }
  __syncthreads();

  unsigned short* pt = &Pt[wv][0];

  for (int qt = wv; qt < 19; qt += 8) {
    // Q B-frags: B[n=qrow=l16][k=d=quad*8+j], d in [0,64)
    int qrow = qt * 16 + l16; if (qrow > 299) qrow = 299;   // clamp; dup cols unused
    const float* qp = Qp + (size_t)(b * NN + qrow) * ldq + qoff + h * 64 + quad * 8;
    short8 qf[2];
#pragma unroll
    for (int ks = 0; ks < 2; ks++) {
      float4 x0 = *(const float4*)(qp + ks * 32);
      float4 x1 = *(const float4*)(qp + ks * 32 + 4);
      union { unsigned u[4]; short8 s; } cv;
      cv.u[0] = pack_bf16x2(x0.x, x0.y); cv.u[1] = pack_bf16x2(x0.z, x0.w);
      cv.u[2] = pack_bf16x2(x1.x, x1.y); cv.u[3] = pack_bf16x2(x1.z, x1.w);
      qf[ks] = cv.s;
    }

    // S' = K Q^T: rows = seq (19 tiles of 16), cols = qrow
    f32x4 sacc[19];
#pragma unroll
    for (int t = 0; t < 19; t++) {
      short8 k0 = *(const short8*)&Ksh[(t * 16 + l16) * 72 + quad * 8];
      short8 k1 = *(const short8*)&Ksh[(t * 16 + l16) * 72 + 32 + quad * 8];
      f32x4 a = (f32x4){0.f, 0.f, 0.f, 0.f};
      a = __builtin_amdgcn_mfma_f32_16x16x32_bf16(k0, qf[0], a, 0, 0, 0);
      a = __builtin_amdgcn_mfma_f32_16x16x32_bf16(k1, qf[1], a, 0, 0, 0);
      sacc[t] = a;
    }

    // softmax over seq for qrow = l16: in-lane over (t,r), cross-quad shfl
    float mx = -1e30f;
#pragma unroll
    for (int t = 0; t < 19; t++)
#pragma unroll
      for (int r = 0; r < 4; r++) mx = fmaxf(mx, sacc[t][r]);
    mx = fmaxf(mx, __shfl_xor(mx, 16));
    mx = fmaxf(mx, __shfl_xor(mx, 32));
    float sum = 0.f;
#pragma unroll
    for (int t = 0; t < 19; t++) {
#pragma unroll
      for (int r = 0; r < 4; r++) {
        float p = __expf((sacc[t][r] - mx) * scale);
        if (t == 18 && quad == 3) p = 0.f;     // seq 300..303 pad
        sacc[t][r] = p; sum += p;
      }
    }
    sum += __shfl_xor(sum, 16);
    sum += __shfl_xor(sum, 32);
    float inv = 1.f / sum;

    // PV: O[qrow][d] = sum_seq P[seq][qrow] V[seq][d]
    f32x4 oacc[4];
#pragma unroll
    for (int dt = 0; dt < 4; dt++) oacc[dt] = (f32x4){0.f, 0.f, 0.f, 0.f};
#pragma unroll
    for (int c = 0; c < 10; c++) {
      // transpose P chunk into A-layout: Pt[qrow=l16][seq_in_chunk]
#pragma unroll
      for (int tic = 0; tic < 2; tic++) {
        int t = 2 * c + tic;
        unsigned w0 = 0u, w1 = 0u;
        if (t < 19) {
          w0 = pack_trunc(sacc[t][0], sacc[t][1]);
          w1 = pack_trunc(sacc[t][2], sacc[t][3]);
        }
        *(unsigned*)&pt[l16 * 40 + tic * 16 + quad * 4]     = w0;
        *(unsigned*)&pt[l16 * 40 + tic * 16 + quad * 4 + 2] = w1;
      }
      short8 pa = *(const short8*)&pt[l16 * 40 + quad * 8];
#pragma unroll
      for (int dt = 0; dt < 4; dt++) {
        short8 vb = *(const short8*)&Vt[(dt * 16 + l16) * 328 + c * 32 + quad * 8];
        oacc[dt] = __builtin_amdgcn_mfma_f32_16x16x32_bf16(pa, vb, oacc[dt], 0, 0, 0);
      }
    }

    // epilogue: O rows = quad*4+r, cols = d = dt*16+l16; scale by 1/rowsum
#pragma unroll
    for (int r = 0; r < 4; r++) {
      int row = qt * 16 + quad * 4 + r;
      float iv = __shfl(inv, quad * 4 + r);
      if (row < 300) {
        float* op = Op + (size_t)(b * NN + row) * DM + h * 64 + l16;
#pragma unroll
        for (int dt = 0; dt < 4; dt++)
          op[dt * 16] = oacc[dt][r] * iv;
      }
    }
  }
}

// =================== column mean over seq + mish(t + mean) ===================
__global__ __launch_bounds__(256) void colmean_mish(
    const float* __restrict__ Y, const float* __restrict__ tvec,
    float* __restrict__ mm)
{
  int g = blockIdx.x * 256 + threadIdx.x;
  int b = g >> 9, d = g & 511;
  const float* yp = Y + (size_t)b * NN * DM + d;
  float s = 0.f;
  for (int n = 0; n < NN; n++) s += yp[(size_t)n * DM];
  float v = tvec[g] + s * (1.f / 300.f);
  float sp = (v > 20.f) ? v : log1pf(__expf(v));
  mm[g] = v * tanhf(sp);
}

// =================== X += (Hw+1)*Y + Hb ===================
__global__ __launch_bounds__(256) void align_apply(
    float* __restrict__ X, const float* __restrict__ Y,
    const float* __restrict__ H)
{
  int idx = blockIdx.x * 256 + threadIdx.x;  // rows*128 float4s
  int row = idx >> 7;
  int d4  = (idx & 127) * 4;
  int b   = row / NN;
  float4 y = *(const float4*)&Y[(size_t)row * DM + d4];
  float4 x = *(const float4*)&X[(size_t)row * DM + d4];
  const float* hw = H + (size_t)b * 1024 + d4;
  const float* hb = hw + 512;
  x.x += (hw[0] + 1.f) * y.x + hb[0];
  x.y += (hw[1] + 1.f) * y.y + hb[1];
  x.z += (hw[2] + 1.f) * y.z + hb[2];
  x.w += (hw[3] + 1.f) * y.w + hb[3];
  *(float4*)&X[(size_t)row * DM + d4] = x;
}

// =================== launch ===================
extern "C" void kernel_launch(void* const* d_in, const int* in_sizes, int n_in,
                              void* d_out, int out_size, void* d_ws, size_t ws_size,
                              hipStream_t stream)
{
  const float* tgt      = (const float*)d_in[0];
  const float* memory   = (const float*)d_in[1];
  const float* tvec     = (const float*)d_in[2];
  const float* qk_w     = (const float*)d_in[3];
  const float* v_w      = (const float*)d_in[4];
  const float* ds_lw    = (const float*)d_in[5];
  const float* ds_lb    = (const float*)d_in[6];
  const float* ta_in_w  = (const float*)d_in[7];
  const float* ta_in_b  = (const float*)d_in[8];
  const float* ta_out_w = (const float*)d_in[9];
  const float* ta_out_b = (const float*)d_in[10];
  const float* ca_in_w  = (const float*)d_in[11];
  const float* ca_in_b  = (const float*)d_in[12];
  const float* ca_out_w = (const float*)d_in[13];
  const float* ca_out_b = (const float*)d_in[14];
  const float* l1_w     = (const float*)d_in[15];
  const float* l1_b     = (const float*)d_in[16];
  const float* l2_w     = (const float*)d_in[17];
  const float* l2_b     = (const float*)d_in[18];
  const float* n1_g = (const float*)d_in[19]; const float* n1_b = (const float*)d_in[20];
  const float* n2_g = (const float*)d_in[21]; const float* n2_b = (const float*)d_in[22];
  const float* n3_g = (const float*)d_in[23]; const float* n3_b = (const float*)d_in[24];
  const float* n4_g = (const float*)d_in[25]; const float* n4_b = (const float*)d_in[26];
  const float* a1_w = (const float*)d_in[27]; const float* a1_b = (const float*)d_in[28];
  const float* a2_w = (const float*)d_in[29]; const float* a2_b = (const float*)d_in[30];
  const float* a3_w = (const float*)d_in[31]; const float* a3_b = (const float*)d_in[32];

  const size_t wtrans_f = 638976ULL + 319488ULL;   // qk_wT + v_wT (floats)
  const size_t per_b = 4306944ULL;                 // bytes per batch element
  int Bc = 128;
  while (Bc > 1 && wtrans_f * 4ULL + (size_t)Bc * per_b > ws_size) Bc >>= 1;
  const int rows = Bc * NN;
  const int mB   = (rows + 127) / 128;
  const int aB   = (Bc + 127) / 128;
  const int nchunks = BB / Bc;

  float* qkT = (float*)d_ws;               // [1248][512]
  float* vT  = qkT + 638976;               // [624][512]
  float* XN  = vT + 319488;                // [rows,512]
  float* T1  = XN + (size_t)rows * 512;    // [rows,1536]
  float* T2  = T1 + (size_t)rows * 1536;   // [rows,1024]
  float* Yb  = T2 + (size_t)rows * 1024;   // [rows,512]
  float* MM  = Yb + (size_t)rows * 512;    // [Bc,512]
  float* Hb  = MM + (size_t)Bc * 512;      // [Bc,1024]

  dim3 thr(256);

  transpose_f32<<<dim3(39, 16), thr, 0, stream>>>(qk_w, qkT, 512, 1248);
  transpose_f32<<<dim3(20, 16), thr, 0, stream>>>(v_w,  vT,  512, 624);

  for (int c = 0; c < nchunks; ++c) {
    const size_t roff = (size_t)c * Bc * NN * DM;
    const float* tgtC = tgt    + roff;
    const float* memC = memory + roff;
    const float* tC   = tvec   + (size_t)c * Bc * 512;
    float*       XC   = (float*)d_out + roff;

    // ---- ds-attention branch: x = tgt + ds_attn(LN1(tgt)) ----
    ln_kernel<<<rows / 4, thr, 0, stream>>>(tgtC, n1_g, n1_b, XN, rows);
    gemm_bf16<0><<<dim3(10, mB), thr, 0, stream>>>(XN, 512, qkT, 512, nullptr, nullptr, 0, T1, 1248, rows, 512, 1248);
    gemm_bf16<0><<<dim3(5, mB),  thr, 0, stream>>>(XN, 512, vT,  512, nullptr, nullptr, 0, T2, 624,  rows, 512, 624);
    ds_attn_kernel<<<rows / 2, thr, 0, stream>>>(T1, T2);
    gemm_bf16<3><<<dim3(4, mB),  thr, 0, stream>>>(T2, 624, ds_lw, 624, ds_lb, tgtC, 512, XC, 512, rows, 624, 512);

    // ---- self attention + align1 ----
    ln_kernel<<<rows / 4, thr, 0, stream>>>(XC, n2_g, n2_b, XN, rows);
    gemm_bf16<1><<<dim3(12, mB), thr, 0, stream>>>(XN, 512, ta_in_w, 512, ta_in_b, nullptr, 0, T1, 1536, rows, 512, 1536);
    mha_mfma<<<Bc * 8, 512, 0, stream>>>(T1, 1536, 0, T1, 1536, 512, 1024, XN, 0.125f);
    gemm_bf16<1><<<dim3(4, mB),  thr, 0, stream>>>(XN, 512, ta_out_w, 512, ta_out_b, nullptr, 0, Yb, 512, rows, 512, 512);
    colmean_mish<<<Bc * 2, thr, 0, stream>>>(Yb, tC, MM);
    gemm_bf16<1><<<dim3(8, aB),  thr, 0, stream>>>(MM, 512, a1_w, 512, a1_b, nullptr, 0, Hb, 1024, Bc, 512, 1024);
    align_apply<<<rows / 2, thr, 0, stream>>>(XC, Yb, Hb);

    // ---- cross attention + align2 ----
    ln_kernel<<<rows / 4, thr, 0, stream>>>(XC, n3_g, n3_b, XN, rows);
    gemm_bf16<1><<<dim3(4, mB),  thr, 0, stream>>>(XN, 512, ca_in_w, 512, ca_in_b, nullptr, 0, T1, 512, rows, 512, 512);
    gemm_bf16<1><<<dim3(8, mB),  thr, 0, stream>>>(memC, 512, ca_in_w + 262144, 512, ca_in_b + 512, nullptr, 0, T2, 1024, rows, 512, 1024);
    mha_mfma<<<Bc * 8, 512, 0, stream>>>(T1, 512, 0, T2, 1024, 0, 512, XN, 0.125f);
    gemm_bf16<1><<<dim3(4, mB),  thr, 0, stream>>>(XN, 512, ca_out_w, 512, ca_out_b, nullptr, 0, Yb, 512, rows, 512, 512);
    colmean_mish<<<Bc * 2, thr, 0, stream>>>(Yb, tC, MM);
    gemm_bf16<1><<<dim3(8, aB),  thr, 0, stream>>>(MM, 512, a2_w, 512, a2_b, nullptr, 0, Hb, 1024, Bc, 512, 1024);
    align_apply<<<rows / 2, thr, 0, stream>>>(XC, Yb, Hb);

    // ---- FFN (2x1024 halves) + align3 ----
    ln_kernel<<<rows / 4, thr, 0, stream>>>(XC, n4_g, n4_b, XN, rows);
    gemm_bf16<2><<<dim3(8, mB),  thr, 0, stream>>>(XN, 512, l1_w, 512, l1_b, nullptr, 0, T2, 1024, rows, 512, 1024);
    gemm_bf16<1><<<dim3(4, mB),  thr, 0, stream>>>(T2, 1024, l2_w, 2048, l2_b, nullptr, 0, Yb, 512, rows, 1024, 512);
    gemm_bf16<2><<<dim3(8, mB),  thr, 0, stream>>>(XN, 512, l1_w + 524288, 512, l1_b + 1024, nullptr, 0, T2, 1024, rows, 512, 1024);
    gemm_bf16<4><<<dim3(4, mB),  thr, 0, stream>>>(T2, 1024, l2_w + 1024, 2048, nullptr, nullptr, 0, Yb, 512, rows, 1024, 512);
    colmean_mish<<<Bc * 2, thr, 0, stream>>>(Yb, tC, MM);
    gemm_bf16<1><<<dim3(8, aB),  thr, 0, stream>>>(MM, 512, a3_w, 512, a3_b, nullptr, 0, Hb, 1024, Bc, 512, 1024);
    align_apply<<<rows / 2, thr, 0, stream>>>(XC, Yb, Hb);
  }
}